// Round 1
// baseline (296.500 us; speedup 1.0000x reference)
//
#include <hip/hip_runtime.h>

// Problem constants
#define BB 4
#define RR 384
#define CC 384
#define EE 512
#define HH 16
#define DD 32
#define MROWS 1536   // B*R = B*C

// ---------------------------------------------------------------------------
// GEMM body: Y[m][n] = sum_k X[m][k] * W[n][k] + bias[n]
// M=1536, N=512, K=512. 64x64 tile, BK=16, 256 threads, 4x4 microtile.
// ---------------------------------------------------------------------------
__device__ __forceinline__ void gemm_xwT_body(const float* __restrict__ X,
                                              const float* __restrict__ W,
                                              const float* __restrict__ bias,
                                              float* __restrict__ Y)
{
    constexpr int K = 512, N = 512;
    __shared__ float As[64][17];   // pad -> conflict-free compute reads
    __shared__ float Bs[16][65];
    const int tid = threadIdx.x;
    const int tx = tid & 15, ty = tid >> 4;
    const int m0 = blockIdx.y << 6, n0 = blockIdx.x << 6;
    const int lr = tid >> 2;          // 0..63
    const int lq = (tid & 3) << 2;    // 0,4,8,12
    float acc[4][4] = {};
    for (int k0 = 0; k0 < K; k0 += 16) {
        float4 av = *(const float4*)(X + (m0 + lr) * K + k0 + lq);
        float4 bv = *(const float4*)(W + (n0 + lr) * K + k0 + lq);
        As[lr][lq + 0] = av.x; As[lr][lq + 1] = av.y;
        As[lr][lq + 2] = av.z; As[lr][lq + 3] = av.w;
        Bs[lq + 0][lr] = bv.x; Bs[lq + 1][lr] = bv.y;
        Bs[lq + 2][lr] = bv.z; Bs[lq + 3][lr] = bv.w;
        __syncthreads();
#pragma unroll
        for (int kk = 0; kk < 16; ++kk) {
            float a[4], b[4];
#pragma unroll
            for (int i = 0; i < 4; ++i) a[i] = As[ty * 4 + i][kk];
#pragma unroll
            for (int j = 0; j < 4; ++j) b[j] = Bs[kk][tx * 4 + j];
#pragma unroll
            for (int i = 0; i < 4; ++i)
#pragma unroll
                for (int j = 0; j < 4; ++j)
                    acc[i][j] = fmaf(a[i], b[j], acc[i][j]);
        }
        __syncthreads();
    }
    const int n = n0 + tx * 4;
    float b0 = bias[n + 0], b1v = bias[n + 1], b2v = bias[n + 2], b3 = bias[n + 3];
#pragma unroll
    for (int i = 0; i < 4; ++i) {
        const int m = m0 + ty * 4 + i;
        float4 o;
        o.x = acc[i][0] + b0;
        o.y = acc[i][1] + b1v;
        o.z = acc[i][2] + b2v;
        o.w = acc[i][3] + b3;
        *(float4*)(Y + m * N + n) = o;
    }
}

__global__ __launch_bounds__(256) void qkv_kernel(
    const float* __restrict__ rowe, const float* __restrict__ cole,
    const float* __restrict__ Wq, const float* __restrict__ Wk, const float* __restrict__ Wv,
    const float* __restrict__ bq, const float* __restrict__ bk, const float* __restrict__ bv,
    float* __restrict__ Qo, float* __restrict__ Ko, float* __restrict__ Vo)
{
    const float* X; const float* W; const float* bias; float* Y;
    if (blockIdx.z == 0)      { X = rowe; W = Wq; bias = bq; Y = Qo; }
    else if (blockIdx.z == 1) { X = cole; W = Wk; bias = bk; Y = Ko; }
    else                      { X = cole; W = Wv; bias = bv; Y = Vo; }
    gemm_xwT_body(X, W, bias, Y);
}

__global__ __launch_bounds__(256) void oproj_kernel(
    const float* __restrict__ Hb, const float* __restrict__ Wo,
    const float* __restrict__ bo, float* __restrict__ out)
{
    gemm_xwT_body(Hb, Wo, bo, out);
}

// ---------------------------------------------------------------------------
// Attention kernel: one block per (b, h, 96-row chunk). 256 threads = 4 waves,
// each wave owns 24 rows. Lanes span c (6 c per lane).
// LDS: K [384][33] pad, V [384][32], Q [96][32], attn row buf [4][384].
// ---------------------------------------------------------------------------
__global__ __launch_bounds__(256) void attn_kernel(
    const float* __restrict__ Qb, const float* __restrict__ Kb, const float* __restrict__ Vb,
    const float* __restrict__ cost,
    const float* __restrict__ W1, const float* __restrict__ b1,
    const float* __restrict__ W2, const float* __restrict__ b2,
    const float* __restrict__ beta,
    float* __restrict__ Hout)
{
    extern __shared__ float smem[];
    float* Ks = smem;                  // 384*33 = 12672
    float* Vs = smem + 12672;          // 384*32 = 12288
    float* Qs = smem + 24960;          // 96*32  = 3072
    float* aw = smem + 28032;          // 4*384  = 1536

    const int tid = threadIdx.x;
    const int chunk = blockIdx.x;      // 0..3
    const int h = blockIdx.y;          // 0..15
    const int b = blockIdx.z;          // 0..3
    const int r0 = chunk * 96;

    // ---- stage K,V (full head) and Q (96-row chunk) into LDS ----
    for (int idx = tid; idx < CC * 8; idx += 256) {
        const int c = idx >> 3, dq = (idx & 7) << 2;
        const int gbase = (b * CC + c) * EE + h * DD + dq;
        float4 kq = *(const float4*)(Kb + gbase);
        Ks[c * 33 + dq + 0] = kq.x; Ks[c * 33 + dq + 1] = kq.y;
        Ks[c * 33 + dq + 2] = kq.z; Ks[c * 33 + dq + 3] = kq.w;
        float4 vq = *(const float4*)(Vb + gbase);
        *(float4*)(Vs + c * 32 + dq) = vq;
    }
    for (int idx = tid; idx < 96 * 8; idx += 256) {
        const int rl = idx >> 3, dq = (idx & 7) << 2;
        *(float4*)(Qs + rl * 32 + dq) =
            *(const float4*)(Qb + (b * RR + r0 + rl) * EE + h * DD + dq);
    }

    // ---- per-head MLP params: uniform addresses -> scalar regs ----
    float w10[16], w11[16], b1h[16], w2h[16];
#pragma unroll
    for (int m = 0; m < 16; ++m) {
        w10[m] = W1[(h * 2 + 0) * 16 + m];
        w11[m] = W1[(h * 2 + 1) * 16 + m];
        b1h[m] = b1[h * 16 + m];
        w2h[m] = W2[h * 16 + m];
    }
    const float b2h = b2[h];
    const float betah = beta[h];
    const float scale = 0.17677669529663687f;  // 1/sqrt(32)

    __syncthreads();

    const int wave = tid >> 6, lane = tid & 63;
    const int dlane = lane & 31, half = lane >> 5;

    for (int i = 0; i < 24; ++i) {
        const int rl = wave * 24 + i;
        const int rg = r0 + rl;

        // Q row into registers
        float qr[32];
#pragma unroll
        for (int d = 0; d < 32; ++d) qr[d] = Qs[rl * 32 + d];

        float sc[6];
#pragma unroll
        for (int j = 0; j < 6; ++j) {
            const int c = lane + 64 * j;
            const float cw = cost[(b * RR + rg) * CC + c];
            float score;
            if (cw > 0.f) {
                float dot = 0.f;
#pragma unroll
                for (int d = 0; d < 32; ++d)
                    dot = fmaf(qr[d], Ks[c * 33 + d], dot);
                dot *= scale;
                float logit = b2h;
#pragma unroll
                for (int m = 0; m < 16; ++m) {
                    float hid = fmaf(dot, w10[m], fmaf(cw, w11[m], b1h[m]));
                    hid = fmaxf(hid, 0.f);
                    logit = fmaf(hid, w2h[m], logit);
                }
                score = tanhf(logit) * 10.f;
            } else {
                score = betah;
            }
            sc[j] = score;
        }

        // ---- 64-lane softmax over 384 scores ----
        float mx = sc[0];
#pragma unroll
        for (int j = 1; j < 6; ++j) mx = fmaxf(mx, sc[j]);
#pragma unroll
        for (int off = 32; off; off >>= 1) mx = fmaxf(mx, __shfl_xor(mx, off));
        float sum = 0.f;
#pragma unroll
        for (int j = 0; j < 6; ++j) {
            float e = __expf(sc[j] - mx);
            sc[j] = e;
            sum += e;
        }
#pragma unroll
        for (int off = 32; off; off >>= 1) sum += __shfl_xor(sum, off);
        const float inv = 1.f / sum;
#pragma unroll
        for (int j = 0; j < 6; ++j) aw[wave * 384 + lane + 64 * j] = sc[j] * inv;
        __syncthreads();

        // ---- PV: lanes 0..31 = d over first 192 c, lanes 32..63 second 192 ----
        float acc = 0.f;
#pragma unroll 8
        for (int cc = 0; cc < 192; ++cc) {
            const int c = half * 192 + cc;
            acc = fmaf(aw[wave * 384 + c], Vs[c * 32 + dlane], acc);
        }
        acc += __shfl_xor(acc, 32);
        if (lane < 32)
            Hout[(b * RR + rg) * EE + h * DD + dlane] = acc;
        __syncthreads();
    }
}

// ---------------------------------------------------------------------------
extern "C" void kernel_launch(void* const* d_in, const int* in_sizes, int n_in,
                              void* d_out, int out_size, void* d_ws, size_t ws_size,
                              hipStream_t stream)
{
    const float* rowe = (const float*)d_in[0];
    const float* cole = (const float*)d_in[1];
    const float* cost = (const float*)d_in[2];
    const float* Wq   = (const float*)d_in[3];
    const float* bq   = (const float*)d_in[4];
    const float* Wk   = (const float*)d_in[5];
    const float* bk   = (const float*)d_in[6];
    const float* Wv   = (const float*)d_in[7];
    const float* bv   = (const float*)d_in[8];
    const float* Wo   = (const float*)d_in[9];
    const float* bo   = (const float*)d_in[10];
    const float* W1   = (const float*)d_in[11];
    const float* b1   = (const float*)d_in[12];
    const float* W2   = (const float*)d_in[13];
    const float* b2   = (const float*)d_in[14];
    const float* beta = (const float*)d_in[15];
    float* out = (float*)d_out;

    float* Qb = (float*)d_ws;                 // 1536*512 f32 = 3 MB
    float* Kb = Qb + MROWS * EE;
    float* Vb = Kb + MROWS * EE;
    float* Hb = Vb + MROWS * EE;              // total 12.6 MB

    dim3 g1(8, 24, 3);
    qkv_kernel<<<g1, 256, 0, stream>>>(rowe, cole, Wq, Wk, Wv, bq, bk, bv, Qb, Kb, Vb);

    dim3 g2(4, 16, 4);
    const size_t lds_bytes = (size_t)(384 * 33 + 384 * 32 + 96 * 32 + 4 * 384) * 4;
    attn_kernel<<<g2, 256, lds_bytes, stream>>>(Qb, Kb, Vb, cost, W1, b1, W2, b2, beta, Hb);

    dim3 g3(8, 24, 1);
    oproj_kernel<<<g3, 256, 0, stream>>>(Hb, Wo, bo, out);
}

// Round 2
// 194.832 us; speedup vs baseline: 1.5218x; 1.5218x over previous
//
#include <hip/hip_runtime.h>

// Problem constants
#define BB 4
#define RR 384
#define CC 384
#define EE 512
#define HH 16
#define DD 32
#define MROWS 1536   // B*R = B*C

// ---------------------------------------------------------------------------
// GEMM body: Y[m][n] = sum_k X[m][k] * W[n][k] + bias[n]
// M=1536, N=512, K=512. 64x64 tile, BK=16, 256 threads, 4x4 microtile.
// ---------------------------------------------------------------------------
__device__ __forceinline__ void gemm_xwT_body(const float* __restrict__ X,
                                              const float* __restrict__ W,
                                              const float* __restrict__ bias,
                                              float* __restrict__ Y)
{
    constexpr int K = 512, N = 512;
    __shared__ float As[64][17];
    __shared__ float Bs[16][65];
    const int tid = threadIdx.x;
    const int tx = tid & 15, ty = tid >> 4;
    const int m0 = blockIdx.y << 6, n0 = blockIdx.x << 6;
    const int lr = tid >> 2;          // 0..63
    const int lq = (tid & 3) << 2;    // 0,4,8,12
    float acc[4][4] = {};
    for (int k0 = 0; k0 < K; k0 += 16) {
        float4 av = *(const float4*)(X + (m0 + lr) * K + k0 + lq);
        float4 bv = *(const float4*)(W + (n0 + lr) * K + k0 + lq);
        As[lr][lq + 0] = av.x; As[lr][lq + 1] = av.y;
        As[lr][lq + 2] = av.z; As[lr][lq + 3] = av.w;
        Bs[lq + 0][lr] = bv.x; Bs[lq + 1][lr] = bv.y;
        Bs[lq + 2][lr] = bv.z; Bs[lq + 3][lr] = bv.w;
        __syncthreads();
#pragma unroll
        for (int kk = 0; kk < 16; ++kk) {
            float a[4], b[4];
#pragma unroll
            for (int i = 0; i < 4; ++i) a[i] = As[ty * 4 + i][kk];
#pragma unroll
            for (int j = 0; j < 4; ++j) b[j] = Bs[kk][tx * 4 + j];
#pragma unroll
            for (int i = 0; i < 4; ++i)
#pragma unroll
                for (int j = 0; j < 4; ++j)
                    acc[i][j] = fmaf(a[i], b[j], acc[i][j]);
        }
        __syncthreads();
    }
    const int n = n0 + tx * 4;
    float b0 = bias[n + 0], b1v = bias[n + 1], b2v = bias[n + 2], b3 = bias[n + 3];
#pragma unroll
    for (int i = 0; i < 4; ++i) {
        const int m = m0 + ty * 4 + i;
        float4 o;
        o.x = acc[i][0] + b0;
        o.y = acc[i][1] + b1v;
        o.z = acc[i][2] + b2v;
        o.w = acc[i][3] + b3;
        *(float4*)(Y + m * N + n) = o;
    }
}

__global__ __launch_bounds__(256) void qkv_kernel(
    const float* __restrict__ rowe, const float* __restrict__ cole,
    const float* __restrict__ Wq, const float* __restrict__ Wk, const float* __restrict__ Wv,
    const float* __restrict__ bq, const float* __restrict__ bk, const float* __restrict__ bv,
    float* __restrict__ Qo, float* __restrict__ Ko, float* __restrict__ Vo)
{
    const float* X; const float* W; const float* bias; float* Y;
    if (blockIdx.z == 0)      { X = rowe; W = Wq; bias = bq; Y = Qo; }
    else if (blockIdx.z == 1) { X = cole; W = Wk; bias = bk; Y = Ko; }
    else                      { X = cole; W = Wv; bias = bv; Y = Vo; }
    gemm_xwT_body(X, W, bias, Y);
}

__global__ __launch_bounds__(256) void oproj_kernel(
    const float* __restrict__ Hb, const float* __restrict__ Wo,
    const float* __restrict__ bo, float* __restrict__ out)
{
    gemm_xwT_body(Hb, Wo, bo, out);
}

// ---------------------------------------------------------------------------
// Vsum kernel: Vsum[b][h][d] = sum_c V[b][c][h*32+d]. Grid (16,4), 256 thr.
// ---------------------------------------------------------------------------
__global__ __launch_bounds__(256) void vsum_kernel(const float* __restrict__ Vb,
                                                   float* __restrict__ Vsum)
{
    __shared__ float part[8][32];
    const int h = blockIdx.x, b = blockIdx.y;
    const int d = threadIdx.x & 31, g = threadIdx.x >> 5;
    float acc = 0.f;
    for (int c = g; c < CC; c += 8)
        acc += Vb[(b * CC + c) * EE + h * DD + d];
    part[g][d] = acc;
    __syncthreads();
    if (g == 0) {
        float s = 0.f;
#pragma unroll
        for (int gg = 0; gg < 8; ++gg) s += part[gg][d];
        Vsum[(b * HH + h) * DD + d] = s;
    }
}

// ---------------------------------------------------------------------------
// Semi-sparse attention: one block per (b, h, 16-row chunk), 4 waves, each
// wave owns 4 rows. Per row: ballot-compact the ~38 edge columns, dot+MLP
// only at edges, analytic background softmax (all non-edges score beta):
//   Z = sum_E exp(s-m) + (C-nE) * exp(beta-m)
//   head = [ sum_E (exp(s-m)-exp(beta-m)) * V_c + exp(beta-m) * Vsum ] / Z
// LDS: Qs 2KB + per-wave edge lists 12KB = 14KB -> occupancy VGPR-bound.
// ---------------------------------------------------------------------------
__global__ __launch_bounds__(256) void attn_kernel(
    const float* __restrict__ Qb, const float* __restrict__ Kb, const float* __restrict__ Vb,
    const float* __restrict__ cost,
    const float* __restrict__ W1, const float* __restrict__ b1,
    const float* __restrict__ W2, const float* __restrict__ b2,
    const float* __restrict__ beta,
    const float* __restrict__ Vsum,
    float* __restrict__ Hout)
{
    __shared__ float Qs[16][32];
    __shared__ int   ecol[4][CC];
    __shared__ float eval[4][CC];

    const int tid = threadIdx.x;
    const int chunk = blockIdx.x;      // 0..23
    const int h = blockIdx.y;          // 0..15
    const int b = blockIdx.z;          // 0..3
    const int r0 = chunk * 16;

    // stage Q chunk
    for (int idx = tid; idx < 16 * 8; idx += 256) {
        const int rl = idx >> 3, dq = (idx & 7) << 2;
        *(float4*)(&Qs[rl][dq]) =
            *(const float4*)(Qb + (b * RR + r0 + rl) * EE + h * DD + dq);
    }

    // per-head MLP params (block-uniform addresses)
    float w10[16], w11[16], b1h[16], w2h[16];
#pragma unroll
    for (int m = 0; m < 16; ++m) {
        w10[m] = W1[(h * 2 + 0) * 16 + m];
        w11[m] = W1[(h * 2 + 1) * 16 + m];
        b1h[m] = b1[h * 16 + m];
        w2h[m] = W2[h * 16 + m];
    }
    const float b2h = b2[h];
    const float betah = beta[h];
    const float scale = 0.17677669529663687f;  // 1/sqrt(32)

    __syncthreads();

    const int wave = tid >> 6, lane = tid & 63;
    int* ec = ecol[wave];
    float* ev = eval[wave];
    const int dlane = lane & 31, half = lane >> 5;
    const unsigned long long prefix = (1ull << lane) - 1ull;

    for (int i = 0; i < 4; ++i) {
        const int rl = wave * 4 + i;
        const int rg = r0 + rl;

        // ---- build compacted edge list via ballot prefix ----
        const float* crow = cost + (b * RR + rg) * CC;
        int nE = 0;
#pragma unroll
        for (int j = 0; j < 6; ++j) {
            const int c = lane + 64 * j;
            const float cw = crow[c];
            const unsigned long long m = __ballot(cw > 0.f);
            if (cw > 0.f) {
                const int slot = nE + __popcll(m & prefix);
                ec[slot] = c;
                ev[slot] = cw;
            }
            nE += __popcll(m);
        }

        // Q row into regs (broadcast LDS reads)
        float qr[32];
#pragma unroll
        for (int d = 0; d < 32; ++d) qr[d] = Qs[rl][d];

        // ---- edge scores: dot + MLP + tanh (1 edge per lane typically) ----
        float smax = betah;
        for (int e = lane; e < nE; e += 64) {
            const int c = ec[e];
            const float cw = ev[e];
            const float* kp = Kb + (b * CC + c) * EE + h * DD;
            float dot = 0.f;
#pragma unroll
            for (int dq = 0; dq < 8; ++dq) {
                const float4 kv = *(const float4*)(kp + dq * 4);
                dot = fmaf(qr[dq * 4 + 0], kv.x, dot);
                dot = fmaf(qr[dq * 4 + 1], kv.y, dot);
                dot = fmaf(qr[dq * 4 + 2], kv.z, dot);
                dot = fmaf(qr[dq * 4 + 3], kv.w, dot);
            }
            dot *= scale;
            float logit = b2h;
#pragma unroll
            for (int m2 = 0; m2 < 16; ++m2) {
                const float hid = fmaf(dot, w10[m2], fmaf(cw, w11[m2], b1h[m2]));
                logit = fmaf(fmaxf(hid, 0.f), w2h[m2], logit);
            }
            const float s = tanhf(logit) * 10.f;
            ev[e] = s;
            smax = fmaxf(smax, s);
        }
#pragma unroll
        for (int off = 32; off; off >>= 1) smax = fmaxf(smax, __shfl_xor(smax, off));

        const float ebeta = __expf(betah - smax);
        float zloc = 0.f;
        for (int e = lane; e < nE; e += 64) {
            const float p = __expf(ev[e] - smax);
            zloc += p;
            ev[e] = p - ebeta;
        }
#pragma unroll
        for (int off = 32; off; off >>= 1) zloc += __shfl_xor(zloc, off);
        const float Z = zloc + (float)(CC - nE) * ebeta;
        const float invZ = 1.f / Z;

        // ---- PV over edges: halves split edges, lanes own d ----
        float acc = 0.f;
        for (int e = half; e < nE; e += 2) {
            acc = fmaf(ev[e], Vb[(b * CC + ec[e]) * EE + h * DD + dlane], acc);
        }
        acc += __shfl_xor(acc, 32);
        if (lane < 32) {
            Hout[(b * RR + rg) * EE + h * DD + dlane] =
                (acc + ebeta * Vsum[(b * HH + h) * DD + dlane]) * invZ;
        }
    }
}

// ---------------------------------------------------------------------------
extern "C" void kernel_launch(void* const* d_in, const int* in_sizes, int n_in,
                              void* d_out, int out_size, void* d_ws, size_t ws_size,
                              hipStream_t stream)
{
    const float* rowe = (const float*)d_in[0];
    const float* cole = (const float*)d_in[1];
    const float* cost = (const float*)d_in[2];
    const float* Wq   = (const float*)d_in[3];
    const float* bq   = (const float*)d_in[4];
    const float* Wk   = (const float*)d_in[5];
    const float* bk   = (const float*)d_in[6];
    const float* Wv   = (const float*)d_in[7];
    const float* bv   = (const float*)d_in[8];
    const float* Wo   = (const float*)d_in[9];
    const float* bo   = (const float*)d_in[10];
    const float* W1   = (const float*)d_in[11];
    const float* b1   = (const float*)d_in[12];
    const float* W2   = (const float*)d_in[13];
    const float* b2   = (const float*)d_in[14];
    const float* beta = (const float*)d_in[15];
    float* out = (float*)d_out;

    float* Qb   = (float*)d_ws;               // each 1536*512 f32 = 3 MB
    float* Kb   = Qb + MROWS * EE;
    float* Vb   = Kb + MROWS * EE;
    float* Hb   = Vb + MROWS * EE;
    float* Vsum = Hb + MROWS * EE;            // 4*16*32 f32 = 8 KB

    dim3 g1(8, 24, 3);
    qkv_kernel<<<g1, 256, 0, stream>>>(rowe, cole, Wq, Wk, Wv, bq, bk, bv, Qb, Kb, Vb);

    dim3 gv(16, 4);
    vsum_kernel<<<gv, 256, 0, stream>>>(Vb, Vsum);

    dim3 g2(24, 16, 4);
    attn_kernel<<<g2, 256, 0, stream>>>(Qb, Kb, Vb, cost, W1, b1, W2, b2, beta, Vsum, Hb);

    dim3 g3(8, 24, 1);
    oproj_kernel<<<g3, 256, 0, stream>>>(Hb, Wo, bo, out);
}

// Round 3
// 161.578 us; speedup vs baseline: 1.8350x; 1.2058x over previous
//
#include <hip/hip_runtime.h>

// Problem constants
#define BB 4
#define RR 384
#define CC 384
#define EE 512
#define HH 16
#define DD 32
#define MROWS 1536   // B*R = B*C

// ---------------------------------------------------------------------------
// GEMM body: Y[m][n] = sum_k X[m][k] * W[n][k] + bias[n]
// M=1536, N=512, K=512. 64x64 tile, BK=16, 256 threads, 4x4 microtile.
// ---------------------------------------------------------------------------
__device__ __forceinline__ void gemm_xwT_body(const float* __restrict__ X,
                                              const float* __restrict__ W,
                                              const float* __restrict__ bias,
                                              float* __restrict__ Y)
{
    constexpr int K = 512, N = 512;
    __shared__ float As[64][17];
    __shared__ float Bs[16][65];
    const int tid = threadIdx.x;
    const int tx = tid & 15, ty = tid >> 4;
    const int m0 = blockIdx.y << 6, n0 = blockIdx.x << 6;
    const int lr = tid >> 2;          // 0..63
    const int lq = (tid & 3) << 2;    // 0,4,8,12
    float acc[4][4] = {};
    for (int k0 = 0; k0 < K; k0 += 16) {
        float4 av = *(const float4*)(X + (m0 + lr) * K + k0 + lq);
        float4 bv = *(const float4*)(W + (n0 + lr) * K + k0 + lq);
        As[lr][lq + 0] = av.x; As[lr][lq + 1] = av.y;
        As[lr][lq + 2] = av.z; As[lr][lq + 3] = av.w;
        Bs[lq + 0][lr] = bv.x; Bs[lq + 1][lr] = bv.y;
        Bs[lq + 2][lr] = bv.z; Bs[lq + 3][lr] = bv.w;
        __syncthreads();
#pragma unroll
        for (int kk = 0; kk < 16; ++kk) {
            float a[4], b[4];
#pragma unroll
            for (int i = 0; i < 4; ++i) a[i] = As[ty * 4 + i][kk];
#pragma unroll
            for (int j = 0; j < 4; ++j) b[j] = Bs[kk][tx * 4 + j];
#pragma unroll
            for (int i = 0; i < 4; ++i)
#pragma unroll
                for (int j = 0; j < 4; ++j)
                    acc[i][j] = fmaf(a[i], b[j], acc[i][j]);
        }
        __syncthreads();
    }
    const int n = n0 + tx * 4;
    float b0 = bias[n + 0], b1v = bias[n + 1], b2v = bias[n + 2], b3 = bias[n + 3];
#pragma unroll
    for (int i = 0; i < 4; ++i) {
        const int m = m0 + ty * 4 + i;
        float4 o;
        o.x = acc[i][0] + b0;
        o.y = acc[i][1] + b1v;
        o.z = acc[i][2] + b2v;
        o.w = acc[i][3] + b3;
        *(float4*)(Y + m * N + n) = o;
    }
}

__global__ __launch_bounds__(256) void qkv_kernel(
    const float* __restrict__ rowe, const float* __restrict__ cole,
    const float* __restrict__ Wq, const float* __restrict__ Wk, const float* __restrict__ Wv,
    const float* __restrict__ bq, const float* __restrict__ bk, const float* __restrict__ bv,
    float* __restrict__ Qo, float* __restrict__ Ko, float* __restrict__ Vo)
{
    const float* X; const float* W; const float* bias; float* Y;
    if (blockIdx.z == 0)      { X = rowe; W = Wq; bias = bq; Y = Qo; }
    else if (blockIdx.z == 1) { X = cole; W = Wk; bias = bk; Y = Ko; }
    else                      { X = cole; W = Wv; bias = bv; Y = Vo; }
    gemm_xwT_body(X, W, bias, Y);
}

__global__ __launch_bounds__(256) void oproj_kernel(
    const float* __restrict__ Hb, const float* __restrict__ Wo,
    const float* __restrict__ bo, float* __restrict__ out)
{
    gemm_xwT_body(Hb, Wo, bo, out);
}

// ---------------------------------------------------------------------------
// Vsum kernel: Vsum[b][h][d] = sum_c V[b][c][h*32+d]. Grid (16,4), 256 thr.
// ---------------------------------------------------------------------------
__global__ __launch_bounds__(256) void vsum_kernel(const float* __restrict__ Vb,
                                                   float* __restrict__ Vsum)
{
    __shared__ float part[8][32];
    const int h = blockIdx.x, b = blockIdx.y;
    const int d = threadIdx.x & 31, g = threadIdx.x >> 5;
    float acc = 0.f;
    for (int c = g; c < CC; c += 8)
        acc += Vb[(b * CC + c) * EE + h * DD + d];
    part[g][d] = acc;
    __syncthreads();
    if (g == 0) {
        float s = 0.f;
#pragma unroll
        for (int gg = 0; gg < 8; ++gg) s += part[gg][d];
        Vsum[(b * HH + h) * DD + d] = s;
    }
}

// ---------------------------------------------------------------------------
// Semi-sparse attention, wave-per-(row, head-half).
// lane = (h = lane&7 [+8 for blockIdx.y==1], g = lane>>3).
// Scoring: 8 heads x 8 edges per chunk, online softmax in registers,
// P redistributed to PV layout via __shfl. LDS = edge list only (3KB).
// Background (non-edge, score=beta) handled analytically via Vsum:
//   out = (apv + e^{beta-m} * (Vsum - aev)) / (Z + (C-nE) e^{beta-m})
// ---------------------------------------------------------------------------
__global__ __launch_bounds__(64) void attn_kernel(
    const float* __restrict__ Qb, const float* __restrict__ Kb, const float* __restrict__ Vb,
    const float* __restrict__ cost,
    const float* __restrict__ W1, const float* __restrict__ b1,
    const float* __restrict__ W2, const float* __restrict__ b2,
    const float* __restrict__ beta,
    const float* __restrict__ Vsum,
    float* __restrict__ Hout)
{
    __shared__ int   ec[CC];
    __shared__ float ecw[CC];

    const int r = blockIdx.x;          // 0..383
    const int hh = blockIdx.y;         // 0..1
    const int b = blockIdx.z;          // 0..3
    const int lane = threadIdx.x;      // 0..63
    const int h = (lane & 7) + hh * 8;
    const int g = lane >> 3;           // 0..7 : eoff (scoring) / dgroup (PV)

    // ---- edge compaction (once per row-wave, shared by 8 heads) ----
    const float* crow = cost + (b * RR + r) * CC;
    int nE = 0;
    const unsigned long long prefix = (1ull << lane) - 1ull;
#pragma unroll
    for (int j = 0; j < 6; ++j) {
        const float cw = crow[lane + 64 * j];
        const unsigned long long mk = __ballot(cw > 0.f);
        if (cw > 0.f) {
            const int slot = nE + __popcll(mk & prefix);
            ec[slot]  = lane + 64 * j;
            ecw[slot] = cw;
        }
        nE += __popcll(mk);
    }
    __syncthreads();

    // ---- per-lane head state ----
    float qr[32];
    {
        const float4* qp = (const float4*)(Qb + (b * RR + r) * EE + h * DD);
#pragma unroll
        for (int dq = 0; dq < 8; ++dq) {
            const float4 v = qp[dq];
            qr[dq * 4 + 0] = v.x; qr[dq * 4 + 1] = v.y;
            qr[dq * 4 + 2] = v.z; qr[dq * 4 + 3] = v.w;
        }
    }
    float w10[16], w11[16], b1h[16], w2h[16];
    {
        const float4* p0 = (const float4*)(W1 + h * 32);
        const float4* p1 = (const float4*)(W1 + h * 32 + 16);
        const float4* pb = (const float4*)(b1 + h * 16);
        const float4* p2 = (const float4*)(W2 + h * 16);
#pragma unroll
        for (int q4 = 0; q4 < 4; ++q4) {
            const float4 a0 = p0[q4], a1 = p1[q4], ab = pb[q4], a2 = p2[q4];
            w10[q4*4+0]=a0.x; w10[q4*4+1]=a0.y; w10[q4*4+2]=a0.z; w10[q4*4+3]=a0.w;
            w11[q4*4+0]=a1.x; w11[q4*4+1]=a1.y; w11[q4*4+2]=a1.z; w11[q4*4+3]=a1.w;
            b1h[q4*4+0]=ab.x; b1h[q4*4+1]=ab.y; b1h[q4*4+2]=ab.z; b1h[q4*4+3]=ab.w;
            w2h[q4*4+0]=a2.x; w2h[q4*4+1]=a2.y; w2h[q4*4+2]=a2.z; w2h[q4*4+3]=a2.w;
        }
    }
    const float b2h = b2[h];
    const float betah = beta[h];
    const float scale = 0.17677669529663687f;  // 1/sqrt(32)

    float m = betah, Z = 0.f;
    float apv[4] = {0.f, 0.f, 0.f, 0.f};
    float aev[4] = {0.f, 0.f, 0.f, 0.f};

    for (int e0 = 0; e0 < nE; e0 += 8) {
        const int e = e0 + g;
        const bool val = e < nE;
        float s = -1e30f;
        if (val) {
            const int c = ec[e];
            const float cw = ecw[e];
            const float* kp = Kb + (b * CC + c) * EE + h * DD;
            float dot = 0.f;
#pragma unroll
            for (int dq = 0; dq < 8; ++dq) {
                const float4 kv = *(const float4*)(kp + dq * 4);
                dot = fmaf(qr[dq * 4 + 0], kv.x, dot);
                dot = fmaf(qr[dq * 4 + 1], kv.y, dot);
                dot = fmaf(qr[dq * 4 + 2], kv.z, dot);
                dot = fmaf(qr[dq * 4 + 3], kv.w, dot);
            }
            dot *= scale;
            float logit = b2h;
#pragma unroll
            for (int mm = 0; mm < 16; ++mm) {
                const float hid = fmaf(dot, w10[mm], fmaf(cw, w11[mm], b1h[mm]));
                logit = fmaf(fmaxf(hid, 0.f), w2h[mm], logit);
            }
            // tanh(x) = 1 - 2/(e^{2x}+1); robust at +-inf
            const float ex = __expf(2.f * logit);
            s = 10.f * (1.f - 2.f / (ex + 1.f));
        }
        // online softmax over the 8 lanes sharing h (xor 8,16,32)
        float cmx = s;
        cmx = fmaxf(cmx, __shfl_xor(cmx, 8));
        cmx = fmaxf(cmx, __shfl_xor(cmx, 16));
        cmx = fmaxf(cmx, __shfl_xor(cmx, 32));
        const float nm = fmaxf(m, cmx);
        const float scl = __expf(m - nm);
        const float p = __expf(s - nm);   // invalid lanes: exp(-1e30-nm)=0
        float cs = p;
        cs += __shfl_xor(cs, 8);
        cs += __shfl_xor(cs, 16);
        cs += __shfl_xor(cs, 32);
        Z = Z * scl + cs;
        m = nm;
#pragma unroll
        for (int k = 0; k < 4; ++k) apv[k] *= scl;

        const int lim = (nE - e0 < 8) ? (nE - e0) : 8;
        for (int eo = 0; eo < lim; ++eo) {
            const float pb = __shfl(p, (lane & 7) + 8 * eo);
            const int cc2 = ec[e0 + eo];     // uniform LDS read -> broadcast
            const float4 vv = *(const float4*)(Vb + (b * CC + cc2) * EE + h * DD + g * 4);
            apv[0] = fmaf(pb, vv.x, apv[0]);
            apv[1] = fmaf(pb, vv.y, apv[1]);
            apv[2] = fmaf(pb, vv.z, apv[2]);
            apv[3] = fmaf(pb, vv.w, apv[3]);
            aev[0] += vv.x; aev[1] += vv.y; aev[2] += vv.z; aev[3] += vv.w;
        }
    }

    const float eb = __expf(betah - m);
    const float inv = 1.f / (Z + (float)(CC - nE) * eb);
    const float4 vs = *(const float4*)(Vsum + (b * HH + h) * DD + g * 4);
    float4 o;
    o.x = (apv[0] + eb * (vs.x - aev[0])) * inv;
    o.y = (apv[1] + eb * (vs.y - aev[1])) * inv;
    o.z = (apv[2] + eb * (vs.z - aev[2])) * inv;
    o.w = (apv[3] + eb * (vs.w - aev[3])) * inv;
    *(float4*)(Hout + (b * RR + r) * EE + h * DD + g * 4) = o;
}

// ---------------------------------------------------------------------------
extern "C" void kernel_launch(void* const* d_in, const int* in_sizes, int n_in,
                              void* d_out, int out_size, void* d_ws, size_t ws_size,
                              hipStream_t stream)
{
    const float* rowe = (const float*)d_in[0];
    const float* cole = (const float*)d_in[1];
    const float* cost = (const float*)d_in[2];
    const float* Wq   = (const float*)d_in[3];
    const float* bq   = (const float*)d_in[4];
    const float* Wk   = (const float*)d_in[5];
    const float* bk   = (const float*)d_in[6];
    const float* Wv   = (const float*)d_in[7];
    const float* bv   = (const float*)d_in[8];
    const float* Wo   = (const float*)d_in[9];
    const float* bo   = (const float*)d_in[10];
    const float* W1   = (const float*)d_in[11];
    const float* b1   = (const float*)d_in[12];
    const float* W2   = (const float*)d_in[13];
    const float* b2   = (const float*)d_in[14];
    const float* beta = (const float*)d_in[15];
    float* out = (float*)d_out;

    float* Qb   = (float*)d_ws;               // each 1536*512 f32 = 3 MB
    float* Kb   = Qb + MROWS * EE;
    float* Vb   = Kb + MROWS * EE;
    float* Hb   = Vb + MROWS * EE;
    float* Vsum = Hb + MROWS * EE;            // 4*16*32 f32 = 8 KB

    dim3 g1(8, 24, 3);
    qkv_kernel<<<g1, 256, 0, stream>>>(rowe, cole, Wq, Wk, Wv, bq, bk, bv, Qb, Kb, Vb);

    dim3 gv(16, 4);
    vsum_kernel<<<gv, 256, 0, stream>>>(Vb, Vsum);

    dim3 g2(RR, 2, BB);
    attn_kernel<<<g2, 64, 0, stream>>>(Qb, Kb, Vb, cost, W1, b1, W2, b2, beta, Vsum, Hb);

    dim3 g3(8, 24, 1);
    oproj_kernel<<<g3, 256, 0, stream>>>(Hb, Wo, bo, out);
}

// Round 4
// 149.444 us; speedup vs baseline: 1.9840x; 1.0812x over previous
//
#include <hip/hip_runtime.h>

// Problem constants
#define BB 4
#define RR 384
#define CC 384
#define EE 512
#define HH 16
#define DD 32
#define MROWS 1536   // B*R = B*C

typedef __attribute__((ext_vector_type(8))) short bf16x8;   // 8 bf16 = 4 VGPRs
typedef __attribute__((ext_vector_type(4))) float f32x4;

// ---------------------------------------------------------------------------
// f32 -> (hi, lo) bf16 split, RNE both times. x ~= hi + lo with ~2^-16 rel err.
// ---------------------------------------------------------------------------
__device__ __forceinline__ void split1(float x, ushort& h, ushort& l)
{
    const unsigned u = __float_as_uint(x);
    const unsigned r = (u + 0x7fffu + ((u >> 16) & 1u)) >> 16;
    h = (ushort)r;
    const float hf = __uint_as_float(r << 16);
    const float lo = x - hf;
    const unsigned u2 = __float_as_uint(lo);
    l = (ushort)((u2 + 0x7fffu + ((u2 >> 16) & 1u)) >> 16);
}

// ---------------------------------------------------------------------------
// Split kernel: 6 arrays -> hi/lo bf16 planes. blockIdx.y selects the array.
// ---------------------------------------------------------------------------
__global__ __launch_bounds__(256) void split_kernel(
    const float* __restrict__ rowe, const float* __restrict__ cole,
    const float* __restrict__ Wq, const float* __restrict__ Wk,
    const float* __restrict__ Wv, const float* __restrict__ Wo,
    ushort* __restrict__ reh, ushort* __restrict__ rel,
    ushort* __restrict__ ceh, ushort* __restrict__ cel,
    ushort* __restrict__ wqh, ushort* __restrict__ wql,
    ushort* __restrict__ wkh, ushort* __restrict__ wkl,
    ushort* __restrict__ wvh, ushort* __restrict__ wvl,
    ushort* __restrict__ woh, ushort* __restrict__ wol)
{
    const float* src; ushort* dh; ushort* dl; int n;
    switch (blockIdx.y) {
    case 0: src = rowe; dh = reh; dl = rel; n = MROWS * EE; break;
    case 1: src = cole; dh = ceh; dl = cel; n = MROWS * EE; break;
    case 2: src = Wq;   dh = wqh; dl = wql; n = EE * EE;    break;
    case 3: src = Wk;   dh = wkh; dl = wkl; n = EE * EE;    break;
    case 4: src = Wv;   dh = wvh; dl = wvl; n = EE * EE;    break;
    default: src = Wo;  dh = woh; dl = wol; n = EE * EE;    break;
    }
    const int i4 = blockIdx.x * 256 + threadIdx.x;
    if (i4 * 4 >= n) return;
    const float4 v = ((const float4*)src)[i4];
    ushort4 hs, ls;
    split1(v.x, hs.x, ls.x);
    split1(v.y, hs.y, ls.y);
    split1(v.z, hs.z, ls.z);
    split1(v.w, hs.w, ls.w);
    ((ushort4*)dh)[i4] = hs;
    ((ushort4*)dl)[i4] = ls;
}

// ---------------------------------------------------------------------------
// bf16x3 emulated-f32 GEMM: Y[m][n] = sum_k A[m][k]*W[n][k] + bias[n].
// M x 512 x 512. Block = 4 waves; wave owns a 16(m) x 64(n) strip.
// Fragment layout (16x16x32): A lane l -> A[l&15][(l>>4)*8 + j];
// B lane l -> B[k][col=l&15], k = (l>>4)*8 + j  == W[l&15][(l>>4)*8+j] (W^T).
// C/D: col = lane&15, row = (lane>>4)*4 + reg  [m89-verified].
// No LDS: operands stream from L1/L2 (W planes are 512 KB, L2-resident).
// ---------------------------------------------------------------------------
__device__ __forceinline__ void gemm_bf16x3_body(
    const ushort* __restrict__ Ahi, const ushort* __restrict__ Alo,
    const ushort* __restrict__ Whi, const ushort* __restrict__ Wlo,
    const float* __restrict__ bias, float* __restrict__ Y)
{
    constexpr int K = 512, N = 512;
    const int wave = threadIdx.x >> 6, lane = threadIdx.x & 63;
    const int row = lane & 15, kgrp = lane >> 4;
    const int m0 = blockIdx.y * 64 + wave * 16;
    const int n0 = blockIdx.x * 64;

    f32x4 acc[4] = {};
    const ushort* aHip = Ahi + (m0 + row) * K + kgrp * 8;
    const ushort* aLop = Alo + (m0 + row) * K + kgrp * 8;

    for (int k0 = 0; k0 < K; k0 += 32) {
        const bf16x8 ah = *(const bf16x8*)(aHip + k0);
        const bf16x8 al = *(const bf16x8*)(aLop + k0);
#pragma unroll
        for (int t = 0; t < 4; ++t) {
            const int wr = (n0 + t * 16 + row) * K + k0 + kgrp * 8;
            const bf16x8 bh = *(const bf16x8*)(Whi + wr);
            const bf16x8 bl = *(const bf16x8*)(Wlo + wr);
            acc[t] = __builtin_amdgcn_mfma_f32_16x16x32_bf16(ah, bh, acc[t], 0, 0, 0);
            acc[t] = __builtin_amdgcn_mfma_f32_16x16x32_bf16(ah, bl, acc[t], 0, 0, 0);
            acc[t] = __builtin_amdgcn_mfma_f32_16x16x32_bf16(al, bh, acc[t], 0, 0, 0);
        }
    }
#pragma unroll
    for (int t = 0; t < 4; ++t) {
        const int n = n0 + t * 16 + row;
        const float bn = bias[n];
#pragma unroll
        for (int j = 0; j < 4; ++j) {
            const int m = m0 + kgrp * 4 + j;
            Y[m * N + n] = acc[t][j] + bn;
        }
    }
}

__global__ __launch_bounds__(256) void qkv_kernel(
    const ushort* __restrict__ reh, const ushort* __restrict__ rel,
    const ushort* __restrict__ ceh, const ushort* __restrict__ cel,
    const ushort* __restrict__ wqh, const ushort* __restrict__ wql,
    const ushort* __restrict__ wkh, const ushort* __restrict__ wkl,
    const ushort* __restrict__ wvh, const ushort* __restrict__ wvl,
    const float* __restrict__ bq, const float* __restrict__ bk,
    const float* __restrict__ bv,
    float* __restrict__ Qo, float* __restrict__ Ko, float* __restrict__ Vo)
{
    if (blockIdx.z == 0)      gemm_bf16x3_body(reh, rel, wqh, wql, bq, Qo);
    else if (blockIdx.z == 1) gemm_bf16x3_body(ceh, cel, wkh, wkl, bk, Ko);
    else                      gemm_bf16x3_body(ceh, cel, wvh, wvl, bv, Vo);
}

__global__ __launch_bounds__(256) void oproj_kernel(
    const ushort* __restrict__ hbh, const ushort* __restrict__ hbl,
    const ushort* __restrict__ woh, const ushort* __restrict__ wol,
    const float* __restrict__ bo, float* __restrict__ out)
{
    gemm_bf16x3_body(hbh, hbl, woh, wol, bo, out);
}

// ---------------------------------------------------------------------------
// Vsum kernel: Vsum[b][h][d] = sum_c V[b][c][h*32+d]. Grid (16,4), 256 thr.
// ---------------------------------------------------------------------------
__global__ __launch_bounds__(256) void vsum_kernel(const float* __restrict__ Vb,
                                                   float* __restrict__ Vsum)
{
    __shared__ float part[8][32];
    const int h = blockIdx.x, b = blockIdx.y;
    const int d = threadIdx.x & 31, g = threadIdx.x >> 5;
    float acc = 0.f;
    for (int c = g; c < CC; c += 8)
        acc += Vb[(b * CC + c) * EE + h * DD + d];
    part[g][d] = acc;
    __syncthreads();
    if (g == 0) {
        float s = 0.f;
#pragma unroll
        for (int gg = 0; gg < 8; ++gg) s += part[gg][d];
        Vsum[(b * HH + h) * DD + d] = s;
    }
}

// ---------------------------------------------------------------------------
// Semi-sparse attention, wave-per-(row, head-half). Unchanged from R3 except
// the epilogue writes Hb as hi/lo bf16 planes for the MFMA output projection.
// ---------------------------------------------------------------------------
__global__ __launch_bounds__(64) void attn_kernel(
    const float* __restrict__ Qb, const float* __restrict__ Kb, const float* __restrict__ Vb,
    const float* __restrict__ cost,
    const float* __restrict__ W1, const float* __restrict__ b1,
    const float* __restrict__ W2, const float* __restrict__ b2,
    const float* __restrict__ beta,
    const float* __restrict__ Vsum,
    ushort* __restrict__ Hbh, ushort* __restrict__ Hbl)
{
    __shared__ int   ec[CC];
    __shared__ float ecw[CC];

    const int r = blockIdx.x;          // 0..383
    const int hh = blockIdx.y;         // 0..1
    const int b = blockIdx.z;          // 0..3
    const int lane = threadIdx.x;      // 0..63
    const int h = (lane & 7) + hh * 8;
    const int g = lane >> 3;           // 0..7 : eoff (scoring) / dgroup (PV)

    // ---- edge compaction (once per row-wave, shared by 8 heads) ----
    const float* crow = cost + (b * RR + r) * CC;
    int nE = 0;
    const unsigned long long prefix = (1ull << lane) - 1ull;
#pragma unroll
    for (int j = 0; j < 6; ++j) {
        const float cw = crow[lane + 64 * j];
        const unsigned long long mk = __ballot(cw > 0.f);
        if (cw > 0.f) {
            const int slot = nE + __popcll(mk & prefix);
            ec[slot]  = lane + 64 * j;
            ecw[slot] = cw;
        }
        nE += __popcll(mk);
    }
    __syncthreads();

    // ---- per-lane head state ----
    float qr[32];
    {
        const float4* qp = (const float4*)(Qb + (b * RR + r) * EE + h * DD);
#pragma unroll
        for (int dq = 0; dq < 8; ++dq) {
            const float4 v = qp[dq];
            qr[dq * 4 + 0] = v.x; qr[dq * 4 + 1] = v.y;
            qr[dq * 4 + 2] = v.z; qr[dq * 4 + 3] = v.w;
        }
    }
    float w10[16], w11[16], b1h[16], w2h[16];
    {
        const float4* p0 = (const float4*)(W1 + h * 32);
        const float4* p1 = (const float4*)(W1 + h * 32 + 16);
        const float4* pb = (const float4*)(b1 + h * 16);
        const float4* p2 = (const float4*)(W2 + h * 16);
#pragma unroll
        for (int q4 = 0; q4 < 4; ++q4) {
            const float4 a0 = p0[q4], a1 = p1[q4], ab = pb[q4], a2 = p2[q4];
            w10[q4*4+0]=a0.x; w10[q4*4+1]=a0.y; w10[q4*4+2]=a0.z; w10[q4*4+3]=a0.w;
            w11[q4*4+0]=a1.x; w11[q4*4+1]=a1.y; w11[q4*4+2]=a1.z; w11[q4*4+3]=a1.w;
            b1h[q4*4+0]=ab.x; b1h[q4*4+1]=ab.y; b1h[q4*4+2]=ab.z; b1h[q4*4+3]=ab.w;
            w2h[q4*4+0]=a2.x; w2h[q4*4+1]=a2.y; w2h[q4*4+2]=a2.z; w2h[q4*4+3]=a2.w;
        }
    }
    const float b2h = b2[h];
    const float betah = beta[h];
    const float scale = 0.17677669529663687f;  // 1/sqrt(32)

    float m = betah, Z = 0.f;
    float apv[4] = {0.f, 0.f, 0.f, 0.f};
    float aev[4] = {0.f, 0.f, 0.f, 0.f};

    for (int e0 = 0; e0 < nE; e0 += 8) {
        const int e = e0 + g;
        const bool val = e < nE;
        float s = -1e30f;
        if (val) {
            const int c = ec[e];
            const float cw = ecw[e];
            const float* kp = Kb + (b * CC + c) * EE + h * DD;
            float dot = 0.f;
#pragma unroll
            for (int dq = 0; dq < 8; ++dq) {
                const float4 kv = *(const float4*)(kp + dq * 4);
                dot = fmaf(qr[dq * 4 + 0], kv.x, dot);
                dot = fmaf(qr[dq * 4 + 1], kv.y, dot);
                dot = fmaf(qr[dq * 4 + 2], kv.z, dot);
                dot = fmaf(qr[dq * 4 + 3], kv.w, dot);
            }
            dot *= scale;
            float logit = b2h;
#pragma unroll
            for (int mm = 0; mm < 16; ++mm) {
                const float hid = fmaf(dot, w10[mm], fmaf(cw, w11[mm], b1h[mm]));
                logit = fmaf(fmaxf(hid, 0.f), w2h[mm], logit);
            }
            const float ex = __expf(2.f * logit);
            s = 10.f * (1.f - 2.f / (ex + 1.f));
        }
        float cmx = s;
        cmx = fmaxf(cmx, __shfl_xor(cmx, 8));
        cmx = fmaxf(cmx, __shfl_xor(cmx, 16));
        cmx = fmaxf(cmx, __shfl_xor(cmx, 32));
        const float nm = fmaxf(m, cmx);
        const float scl = __expf(m - nm);
        const float p = __expf(s - nm);
        float cs = p;
        cs += __shfl_xor(cs, 8);
        cs += __shfl_xor(cs, 16);
        cs += __shfl_xor(cs, 32);
        Z = Z * scl + cs;
        m = nm;
#pragma unroll
        for (int k = 0; k < 4; ++k) apv[k] *= scl;

        const int lim = (nE - e0 < 8) ? (nE - e0) : 8;
        for (int eo = 0; eo < lim; ++eo) {
            const float pb = __shfl(p, (lane & 7) + 8 * eo);
            const int cc2 = ec[e0 + eo];
            const float4 vv = *(const float4*)(Vb + (b * CC + cc2) * EE + h * DD + g * 4);
            apv[0] = fmaf(pb, vv.x, apv[0]);
            apv[1] = fmaf(pb, vv.y, apv[1]);
            apv[2] = fmaf(pb, vv.z, apv[2]);
            apv[3] = fmaf(pb, vv.w, apv[3]);
            aev[0] += vv.x; aev[1] += vv.y; aev[2] += vv.z; aev[3] += vv.w;
        }
    }

    const float eb = __expf(betah - m);
    const float inv = 1.f / (Z + (float)(CC - nE) * eb);
    const float4 vs = *(const float4*)(Vsum + (b * HH + h) * DD + g * 4);
    float4 o;
    o.x = (apv[0] + eb * (vs.x - aev[0])) * inv;
    o.y = (apv[1] + eb * (vs.y - aev[1])) * inv;
    o.z = (apv[2] + eb * (vs.z - aev[2])) * inv;
    o.w = (apv[3] + eb * (vs.w - aev[3])) * inv;

    const int idx = (b * RR + r) * EE + h * DD + g * 4;
    ushort4 oh, ol;
    split1(o.x, oh.x, ol.x);
    split1(o.y, oh.y, ol.y);
    split1(o.z, oh.z, ol.z);
    split1(o.w, oh.w, ol.w);
    *(ushort4*)(Hbh + idx) = oh;
    *(ushort4*)(Hbl + idx) = ol;
}

// ---------------------------------------------------------------------------
extern "C" void kernel_launch(void* const* d_in, const int* in_sizes, int n_in,
                              void* d_out, int out_size, void* d_ws, size_t ws_size,
                              hipStream_t stream)
{
    const float* rowe = (const float*)d_in[0];
    const float* cole = (const float*)d_in[1];
    const float* cost = (const float*)d_in[2];
    const float* Wq   = (const float*)d_in[3];
    const float* bq   = (const float*)d_in[4];
    const float* Wk   = (const float*)d_in[5];
    const float* bk   = (const float*)d_in[6];
    const float* Wv   = (const float*)d_in[7];
    const float* bv   = (const float*)d_in[8];
    const float* Wo   = (const float*)d_in[9];
    const float* bo   = (const float*)d_in[10];
    const float* W1   = (const float*)d_in[11];
    const float* b1   = (const float*)d_in[12];
    const float* W2   = (const float*)d_in[13];
    const float* b2   = (const float*)d_in[14];
    const float* beta = (const float*)d_in[15];
    float* out = (float*)d_out;

    // ---- workspace carve ----
    char* cur = (char*)d_ws;
    float* Qb   = (float*)cur; cur += (size_t)MROWS * EE * 4;
    float* Kb   = (float*)cur; cur += (size_t)MROWS * EE * 4;
    float* Vb   = (float*)cur; cur += (size_t)MROWS * EE * 4;
    float* Vsum = (float*)cur; cur += (size_t)BB * HH * DD * 4;
    ushort* reh = (ushort*)cur; cur += (size_t)MROWS * EE * 2;
    ushort* rel = (ushort*)cur; cur += (size_t)MROWS * EE * 2;
    ushort* ceh = (ushort*)cur; cur += (size_t)MROWS * EE * 2;
    ushort* cel = (ushort*)cur; cur += (size_t)MROWS * EE * 2;
    ushort* wqh = (ushort*)cur; cur += (size_t)EE * EE * 2;
    ushort* wql = (ushort*)cur; cur += (size_t)EE * EE * 2;
    ushort* wkh = (ushort*)cur; cur += (size_t)EE * EE * 2;
    ushort* wkl = (ushort*)cur; cur += (size_t)EE * EE * 2;
    ushort* wvh = (ushort*)cur; cur += (size_t)EE * EE * 2;
    ushort* wvl = (ushort*)cur; cur += (size_t)EE * EE * 2;
    ushort* woh = (ushort*)cur; cur += (size_t)EE * EE * 2;
    ushort* wol = (ushort*)cur; cur += (size_t)EE * EE * 2;
    ushort* hbh = (ushort*)cur; cur += (size_t)MROWS * EE * 2;
    ushort* hbl = (ushort*)cur; cur += (size_t)MROWS * EE * 2;

    split_kernel<<<dim3(768, 6), 256, 0, stream>>>(
        rowe, cole, Wq, Wk, Wv, Wo,
        reh, rel, ceh, cel, wqh, wql, wkh, wkl, wvh, wvl, woh, wol);

    dim3 g1(8, 24, 3);
    qkv_kernel<<<g1, 256, 0, stream>>>(reh, rel, ceh, cel,
                                       wqh, wql, wkh, wkl, wvh, wvl,
                                       bq, bk, bv, Qb, Kb, Vb);

    dim3 gv(16, 4);
    vsum_kernel<<<gv, 256, 0, stream>>>(Vb, Vsum);

    dim3 g2(RR, 2, BB);
    attn_kernel<<<g2, 64, 0, stream>>>(Qb, Kb, Vb, cost, W1, b1, W2, b2, beta,
                                       Vsum, hbh, hbl);

    dim3 g3(8, 24, 1);
    oproj_kernel<<<g3, 256, 0, stream>>>(hbh, hbl, woh, wol, bo, out);
}

// Round 5
// 101.820 us; speedup vs baseline: 2.9120x; 1.4677x over previous
//
#include <hip/hip_runtime.h>

// Problem constants
#define BB 4
#define RR 384
#define CC 384
#define EE 512
#define HH 16
#define DD 32
#define MROWS 1536   // B*R = B*C

typedef __attribute__((ext_vector_type(8))) short bf16x8;   // 8 bf16 = 4 VGPRs
typedef __attribute__((ext_vector_type(4))) float f32x4;

// ---------------------------------------------------------------------------
// f32 -> (hi, lo) bf16 split, RNE both times. x ~= hi + lo with ~2^-16 rel err.
// ---------------------------------------------------------------------------
__device__ __forceinline__ void split1(float x, ushort& h, ushort& l)
{
    const unsigned u = __float_as_uint(x);
    const unsigned r = (u + 0x7fffu + ((u >> 16) & 1u)) >> 16;
    h = (ushort)r;
    const float hf = __uint_as_float(r << 16);
    const float lo = x - hf;
    const unsigned u2 = __float_as_uint(lo);
    l = (ushort)((u2 + 0x7fffu + ((u2 >> 16) & 1u)) >> 16);
}

// Packed fragment address for element (r, k) of a [rows][512] matrix:
// lane l of the wave covering (r-tile, k-tile) reads elems [l*8, l*8+8).
__device__ __forceinline__ int packed_addr(int r, int k)
{
    return ((r >> 4) * 16 + (k >> 5)) * 512 + ((k >> 3) & 3) * 128 + (r & 15) * 8 + (k & 7);
}

// ---------------------------------------------------------------------------
// Split kernel: 6 arrays -> hi/lo bf16 planes in PACKED fragment layout.
// ---------------------------------------------------------------------------
__global__ __launch_bounds__(256) void split_kernel(
    const float* __restrict__ rowe, const float* __restrict__ cole,
    const float* __restrict__ Wq, const float* __restrict__ Wk,
    const float* __restrict__ Wv, const float* __restrict__ Wo,
    ushort* __restrict__ reh, ushort* __restrict__ rel,
    ushort* __restrict__ ceh, ushort* __restrict__ cel,
    ushort* __restrict__ wqh, ushort* __restrict__ wql,
    ushort* __restrict__ wkh, ushort* __restrict__ wkl,
    ushort* __restrict__ wvh, ushort* __restrict__ wvl,
    ushort* __restrict__ woh, ushort* __restrict__ wol)
{
    const float* src; ushort* dh; ushort* dl; int n;
    switch (blockIdx.y) {
    case 0: src = rowe; dh = reh; dl = rel; n = MROWS * EE; break;
    case 1: src = cole; dh = ceh; dl = cel; n = MROWS * EE; break;
    case 2: src = Wq;   dh = wqh; dl = wql; n = EE * EE;    break;
    case 3: src = Wk;   dh = wkh; dl = wkl; n = EE * EE;    break;
    case 4: src = Wv;   dh = wvh; dl = wvl; n = EE * EE;    break;
    default: src = Wo;  dh = woh; dl = wol; n = EE * EE;    break;
    }
    const int i4 = blockIdx.x * 256 + threadIdx.x;
    if (i4 * 4 >= n) return;
    const float4 v = ((const float4*)src)[i4];
    ushort4 hs, ls;
    split1(v.x, hs.x, ls.x);
    split1(v.y, hs.y, ls.y);
    split1(v.z, hs.z, ls.z);
    split1(v.w, hs.w, ls.w);
    const int e0 = i4 * 4;
    const int dst = packed_addr(e0 >> 9, e0 & 511);   // (k&7) in {0,4}: aligned
    *(ushort4*)(dh + dst) = hs;
    *(ushort4*)(dl + dst) = ls;
}

// ---------------------------------------------------------------------------
// bf16x3 emulated-f32 GEMM on packed operands.
// Wave owns m-tile Mt (16 rows) x 4 n-tiles (64 cols). Every operand load is
// one contiguous 1KB wave transaction; depth-1 register pipeline on K.
// ---------------------------------------------------------------------------
__device__ __forceinline__ void gemm_bf16x3_body(
    const ushort* __restrict__ Ahi, const ushort* __restrict__ Alo,
    const ushort* __restrict__ Whi, const ushort* __restrict__ Wlo,
    const float* __restrict__ bias, float* __restrict__ Y,
    int Mt, int Nt0)
{
    constexpr int N = 512;
    const int lane = threadIdx.x & 63;
    const int col = lane & 15, kgrp = lane >> 4;

    const ushort* pah = Ahi + (size_t)Mt * 8192 + lane * 8;
    const ushort* pal = Alo + (size_t)Mt * 8192 + lane * 8;
    const ushort* pbh = Whi + (size_t)Nt0 * 8192 + lane * 8;
    const ushort* pbl = Wlo + (size_t)Nt0 * 8192 + lane * 8;

    f32x4 acc0 = {}, acc1 = {}, acc2 = {}, acc3 = {};

    bf16x8 ah  = *(const bf16x8*)(pah);
    bf16x8 al  = *(const bf16x8*)(pal);
    bf16x8 bh0 = *(const bf16x8*)(pbh);
    bf16x8 bh1 = *(const bf16x8*)(pbh + 8192);
    bf16x8 bh2 = *(const bf16x8*)(pbh + 16384);
    bf16x8 bh3 = *(const bf16x8*)(pbh + 24576);
    bf16x8 bl0 = *(const bf16x8*)(pbl);
    bf16x8 bl1 = *(const bf16x8*)(pbl + 8192);
    bf16x8 bl2 = *(const bf16x8*)(pbl + 16384);
    bf16x8 bl3 = *(const bf16x8*)(pbl + 24576);

#pragma unroll 4
    for (int kt = 0; kt < 16; ++kt) {
        bf16x8 nah = ah, nal = al;
        bf16x8 nbh0 = bh0, nbh1 = bh1, nbh2 = bh2, nbh3 = bh3;
        bf16x8 nbl0 = bl0, nbl1 = bl1, nbl2 = bl2, nbl3 = bl3;
        if (kt < 15) {
            const int ko = (kt + 1) * 512;
            nah  = *(const bf16x8*)(pah + ko);
            nal  = *(const bf16x8*)(pal + ko);
            nbh0 = *(const bf16x8*)(pbh + ko);
            nbh1 = *(const bf16x8*)(pbh + ko + 8192);
            nbh2 = *(const bf16x8*)(pbh + ko + 16384);
            nbh3 = *(const bf16x8*)(pbh + ko + 24576);
            nbl0 = *(const bf16x8*)(pbl + ko);
            nbl1 = *(const bf16x8*)(pbl + ko + 8192);
            nbl2 = *(const bf16x8*)(pbl + ko + 16384);
            nbl3 = *(const bf16x8*)(pbl + ko + 24576);
        }
        acc0 = __builtin_amdgcn_mfma_f32_16x16x32_bf16(ah, bh0, acc0, 0, 0, 0);
        acc0 = __builtin_amdgcn_mfma_f32_16x16x32_bf16(ah, bl0, acc0, 0, 0, 0);
        acc0 = __builtin_amdgcn_mfma_f32_16x16x32_bf16(al, bh0, acc0, 0, 0, 0);
        acc1 = __builtin_amdgcn_mfma_f32_16x16x32_bf16(ah, bh1, acc1, 0, 0, 0);
        acc1 = __builtin_amdgcn_mfma_f32_16x16x32_bf16(ah, bl1, acc1, 0, 0, 0);
        acc1 = __builtin_amdgcn_mfma_f32_16x16x32_bf16(al, bh1, acc1, 0, 0, 0);
        acc2 = __builtin_amdgcn_mfma_f32_16x16x32_bf16(ah, bh2, acc2, 0, 0, 0);
        acc2 = __builtin_amdgcn_mfma_f32_16x16x32_bf16(ah, bl2, acc2, 0, 0, 0);
        acc2 = __builtin_amdgcn_mfma_f32_16x16x32_bf16(al, bh2, acc2, 0, 0, 0);
        acc3 = __builtin_amdgcn_mfma_f32_16x16x32_bf16(ah, bh3, acc3, 0, 0, 0);
        acc3 = __builtin_amdgcn_mfma_f32_16x16x32_bf16(ah, bl3, acc3, 0, 0, 0);
        acc3 = __builtin_amdgcn_mfma_f32_16x16x32_bf16(al, bh3, acc3, 0, 0, 0);
        ah = nah; al = nal;
        bh0 = nbh0; bh1 = nbh1; bh2 = nbh2; bh3 = nbh3;
        bl0 = nbl0; bl1 = nbl1; bl2 = nbl2; bl3 = nbl3;
    }

    const f32x4 accs[4] = {acc0, acc1, acc2, acc3};
#pragma unroll
    for (int t = 0; t < 4; ++t) {
        const int n = (Nt0 + t) * 16 + col;
        const float bn = bias[n];
#pragma unroll
        for (int j = 0; j < 4; ++j) {
            const int m = Mt * 16 + kgrp * 4 + j;
            Y[m * N + n] = accs[t][j] + bn;
        }
    }
}

// XCD-grouping swizzle: l = a + 8b + 64c (a,b in [0,8), c in [0,3))
//  -> Bm = 3a + c (m-strip), Bx = b. Same-Bm blocks share l%8 -> same XCD.
__global__ __launch_bounds__(256) void qkv_kernel(
    const ushort* __restrict__ reh, const ushort* __restrict__ rel,
    const ushort* __restrict__ ceh, const ushort* __restrict__ cel,
    const ushort* __restrict__ wqh, const ushort* __restrict__ wql,
    const ushort* __restrict__ wkh, const ushort* __restrict__ wkl,
    const ushort* __restrict__ wvh, const ushort* __restrict__ wvl,
    const float* __restrict__ bq, const float* __restrict__ bk,
    const float* __restrict__ bv,
    float* __restrict__ Qo, float* __restrict__ Ko, float* __restrict__ Vo)
{
    const int l = blockIdx.x + (blockIdx.y << 3);
    const int Bm = (l & 7) * 3 + (l >> 6);
    const int Bx = (l >> 3) & 7;
    const int Mt = Bm * 4 + (threadIdx.x >> 6);
    const int Nt0 = Bx * 4;
    if (blockIdx.z == 0)      gemm_bf16x3_body(reh, rel, wqh, wql, bq, Qo, Mt, Nt0);
    else if (blockIdx.z == 1) gemm_bf16x3_body(ceh, cel, wkh, wkl, bk, Ko, Mt, Nt0);
    else                      gemm_bf16x3_body(ceh, cel, wvh, wvl, bv, Vo, Mt, Nt0);
}

__global__ __launch_bounds__(256) void oproj_kernel(
    const ushort* __restrict__ hbh, const ushort* __restrict__ hbl,
    const ushort* __restrict__ woh, const ushort* __restrict__ wol,
    const float* __restrict__ bo, float* __restrict__ out)
{
    const int l = blockIdx.x + (blockIdx.y << 3);
    const int Bm = (l & 7) * 3 + (l >> 6);
    const int Bx = (l >> 3) & 7;
    const int Mt = Bm * 4 + (threadIdx.x >> 6);
    const int Nt0 = Bx * 4;
    gemm_bf16x3_body(hbh, hbl, woh, wol, bo, out, Mt, Nt0);
}

// ---------------------------------------------------------------------------
// Vsum kernel: Vsum[b][h][d] = sum_c V[b][c][h*32+d]. Grid (16,4), 256 thr.
// ---------------------------------------------------------------------------
__global__ __launch_bounds__(256) void vsum_kernel(const float* __restrict__ Vb,
                                                   float* __restrict__ Vsum)
{
    __shared__ float part[8][32];
    const int h = blockIdx.x, b = blockIdx.y;
    const int d = threadIdx.x & 31, g = threadIdx.x >> 5;
    float acc = 0.f;
    for (int c = g; c < CC; c += 8)
        acc += Vb[(b * CC + c) * EE + h * DD + d];
    part[g][d] = acc;
    __syncthreads();
    if (g == 0) {
        float s = 0.f;
#pragma unroll
        for (int gg = 0; gg < 8; ++gg) s += part[gg][d];
        Vsum[(b * HH + h) * DD + d] = s;
    }
}

// ---------------------------------------------------------------------------
// Semi-sparse attention, wave-per-(row, head-half). Epilogue writes Hb in
// PACKED hi/lo bf16 layout for the MFMA output projection.
// ---------------------------------------------------------------------------
__global__ __launch_bounds__(64) void attn_kernel(
    const float* __restrict__ Qb, const float* __restrict__ Kb, const float* __restrict__ Vb,
    const float* __restrict__ cost,
    const float* __restrict__ W1, const float* __restrict__ b1,
    const float* __restrict__ W2, const float* __restrict__ b2,
    const float* __restrict__ beta,
    const float* __restrict__ Vsum,
    ushort* __restrict__ Hbh, ushort* __restrict__ Hbl)
{
    __shared__ int   ec[CC];
    __shared__ float ecw[CC];

    const int r = blockIdx.x;          // 0..383
    const int hh = blockIdx.y;         // 0..1
    const int b = blockIdx.z;          // 0..3
    const int lane = threadIdx.x;      // 0..63
    const int h = (lane & 7) + hh * 8;
    const int g = lane >> 3;           // 0..7 : eoff (scoring) / dgroup (PV)

    // ---- edge compaction (once per row-wave, shared by 8 heads) ----
    const float* crow = cost + (b * RR + r) * CC;
    int nE = 0;
    const unsigned long long prefix = (1ull << lane) - 1ull;
#pragma unroll
    for (int j = 0; j < 6; ++j) {
        const float cw = crow[lane + 64 * j];
        const unsigned long long mk = __ballot(cw > 0.f);
        if (cw > 0.f) {
            const int slot = nE + __popcll(mk & prefix);
            ec[slot]  = lane + 64 * j;
            ecw[slot] = cw;
        }
        nE += __popcll(mk);
    }
    __syncthreads();

    // ---- per-lane head state ----
    float qr[32];
    {
        const float4* qp = (const float4*)(Qb + (b * RR + r) * EE + h * DD);
#pragma unroll
        for (int dq = 0; dq < 8; ++dq) {
            const float4 v = qp[dq];
            qr[dq * 4 + 0] = v.x; qr[dq * 4 + 1] = v.y;
            qr[dq * 4 + 2] = v.z; qr[dq * 4 + 3] = v.w;
        }
    }
    float w10[16], w11[16], b1h[16], w2h[16];
    {
        const float4* p0 = (const float4*)(W1 + h * 32);
        const float4* p1 = (const float4*)(W1 + h * 32 + 16);
        const float4* pb = (const float4*)(b1 + h * 16);
        const float4* p2 = (const float4*)(W2 + h * 16);
#pragma unroll
        for (int q4 = 0; q4 < 4; ++q4) {
            const float4 a0 = p0[q4], a1 = p1[q4], ab = pb[q4], a2 = p2[q4];
            w10[q4*4+0]=a0.x; w10[q4*4+1]=a0.y; w10[q4*4+2]=a0.z; w10[q4*4+3]=a0.w;
            w11[q4*4+0]=a1.x; w11[q4*4+1]=a1.y; w11[q4*4+2]=a1.z; w11[q4*4+3]=a1.w;
            b1h[q4*4+0]=ab.x; b1h[q4*4+1]=ab.y; b1h[q4*4+2]=ab.z; b1h[q4*4+3]=ab.w;
            w2h[q4*4+0]=a2.x; w2h[q4*4+1]=a2.y; w2h[q4*4+2]=a2.z; w2h[q4*4+3]=a2.w;
        }
    }
    const float b2h = b2[h];
    const float betah = beta[h];
    const float scale = 0.17677669529663687f;  // 1/sqrt(32)

    float m = betah, Z = 0.f;
    float apv[4] = {0.f, 0.f, 0.f, 0.f};
    float aev[4] = {0.f, 0.f, 0.f, 0.f};

    for (int e0 = 0; e0 < nE; e0 += 8) {
        const int e = e0 + g;
        const bool val = e < nE;
        float s = -1e30f;
        if (val) {
            const int c = ec[e];
            const float cw = ecw[e];
            const float* kp = Kb + (b * CC + c) * EE + h * DD;
            float dot = 0.f;
#pragma unroll
            for (int dq = 0; dq < 8; ++dq) {
                const float4 kv = *(const float4*)(kp + dq * 4);
                dot = fmaf(qr[dq * 4 + 0], kv.x, dot);
                dot = fmaf(qr[dq * 4 + 1], kv.y, dot);
                dot = fmaf(qr[dq * 4 + 2], kv.z, dot);
                dot = fmaf(qr[dq * 4 + 3], kv.w, dot);
            }
            dot *= scale;
            float logit = b2h;
#pragma unroll
            for (int mm = 0; mm < 16; ++mm) {
                const float hid = fmaf(dot, w10[mm], fmaf(cw, w11[mm], b1h[mm]));
                logit = fmaf(fmaxf(hid, 0.f), w2h[mm], logit);
            }
            const float ex = __expf(2.f * logit);
            s = 10.f * (1.f - 2.f / (ex + 1.f));
        }
        float cmx = s;
        cmx = fmaxf(cmx, __shfl_xor(cmx, 8));
        cmx = fmaxf(cmx, __shfl_xor(cmx, 16));
        cmx = fmaxf(cmx, __shfl_xor(cmx, 32));
        const float nm = fmaxf(m, cmx);
        const float scl = __expf(m - nm);
        const float p = __expf(s - nm);
        float cs = p;
        cs += __shfl_xor(cs, 8);
        cs += __shfl_xor(cs, 16);
        cs += __shfl_xor(cs, 32);
        Z = Z * scl + cs;
        m = nm;
#pragma unroll
        for (int k = 0; k < 4; ++k) apv[k] *= scl;

        const int lim = (nE - e0 < 8) ? (nE - e0) : 8;
        for (int eo = 0; eo < lim; ++eo) {
            const float pb = __shfl(p, (lane & 7) + 8 * eo);
            const int cc2 = ec[e0 + eo];
            const float4 vv = *(const float4*)(Vb + (b * CC + cc2) * EE + h * DD + g * 4);
            apv[0] = fmaf(pb, vv.x, apv[0]);
            apv[1] = fmaf(pb, vv.y, apv[1]);
            apv[2] = fmaf(pb, vv.z, apv[2]);
            apv[3] = fmaf(pb, vv.w, apv[3]);
            aev[0] += vv.x; aev[1] += vv.y; aev[2] += vv.z; aev[3] += vv.w;
        }
    }

    const float eb = __expf(betah - m);
    const float inv = 1.f / (Z + (float)(CC - nE) * eb);
    const float4 vs = *(const float4*)(Vsum + (b * HH + h) * DD + g * 4);
    float4 o;
    o.x = (apv[0] + eb * (vs.x - aev[0])) * inv;
    o.y = (apv[1] + eb * (vs.y - aev[1])) * inv;
    o.z = (apv[2] + eb * (vs.z - aev[2])) * inv;
    o.w = (apv[3] + eb * (vs.w - aev[3])) * inv;

    ushort4 oh, ol;
    split1(o.x, oh.x, ol.x);
    split1(o.y, oh.y, ol.y);
    split1(o.z, oh.z, ol.z);
    split1(o.w, oh.w, ol.w);
    // packed write: r_m = b*RR+r, k = h*32 + g*4
    const int rm = b * RR + r;
    const int dstp = ((rm >> 4) * 16 + h) * 512 + (g >> 1) * 128 + (rm & 15) * 8 + (g & 1) * 4;
    *(ushort4*)(Hbh + dstp) = oh;
    *(ushort4*)(Hbl + dstp) = ol;
}

// ---------------------------------------------------------------------------
extern "C" void kernel_launch(void* const* d_in, const int* in_sizes, int n_in,
                              void* d_out, int out_size, void* d_ws, size_t ws_size,
                              hipStream_t stream)
{
    const float* rowe = (const float*)d_in[0];
    const float* cole = (const float*)d_in[1];
    const float* cost = (const float*)d_in[2];
    const float* Wq   = (const float*)d_in[3];
    const float* bq   = (const float*)d_in[4];
    const float* Wk   = (const float*)d_in[5];
    const float* bk   = (const float*)d_in[6];
    const float* Wv   = (const float*)d_in[7];
    const float* bv   = (const float*)d_in[8];
    const float* Wo   = (const float*)d_in[9];
    const float* bo   = (const float*)d_in[10];
    const float* W1   = (const float*)d_in[11];
    const float* b1   = (const float*)d_in[12];
    const float* W2   = (const float*)d_in[13];
    const float* b2   = (const float*)d_in[14];
    const float* beta = (const float*)d_in[15];
    float* out = (float*)d_out;

    // ---- workspace carve ----
    char* cur = (char*)d_ws;
    float* Qb   = (float*)cur; cur += (size_t)MROWS * EE * 4;
    float* Kb   = (float*)cur; cur += (size_t)MROWS * EE * 4;
    float* Vb   = (float*)cur; cur += (size_t)MROWS * EE * 4;
    float* Vsum = (float*)cur; cur += (size_t)BB * HH * DD * 4;
    ushort* reh = (ushort*)cur; cur += (size_t)MROWS * EE * 2;
    ushort* rel = (ushort*)cur; cur += (size_t)MROWS * EE * 2;
    ushort* ceh = (ushort*)cur; cur += (size_t)MROWS * EE * 2;
    ushort* cel = (ushort*)cur; cur += (size_t)MROWS * EE * 2;
    ushort* wqh = (ushort*)cur; cur += (size_t)EE * EE * 2;
    ushort* wql = (ushort*)cur; cur += (size_t)EE * EE * 2;
    ushort* wkh = (ushort*)cur; cur += (size_t)EE * EE * 2;
    ushort* wkl = (ushort*)cur; cur += (size_t)EE * EE * 2;
    ushort* wvh = (ushort*)cur; cur += (size_t)EE * EE * 2;
    ushort* wvl = (ushort*)cur; cur += (size_t)EE * EE * 2;
    ushort* woh = (ushort*)cur; cur += (size_t)EE * EE * 2;
    ushort* wol = (ushort*)cur; cur += (size_t)EE * EE * 2;
    ushort* hbh = (ushort*)cur; cur += (size_t)MROWS * EE * 2;
    ushort* hbl = (ushort*)cur; cur += (size_t)MROWS * EE * 2;

    split_kernel<<<dim3(768, 6), 256, 0, stream>>>(
        rowe, cole, Wq, Wk, Wv, Wo,
        reh, rel, ceh, cel, wqh, wql, wkh, wkl, wvh, wvl, woh, wol);

    dim3 g1(8, 24, 3);
    qkv_kernel<<<g1, 256, 0, stream>>>(reh, rel, ceh, cel,
                                       wqh, wql, wkh, wkl, wvh, wvl,
                                       bq, bk, bv, Qb, Kb, Vb);

    dim3 gv(16, 4);
    vsum_kernel<<<gv, 256, 0, stream>>>(Vb, Vsum);

    dim3 g2(RR, 2, BB);
    attn_kernel<<<g2, 64, 0, stream>>>(Qb, Kb, Vb, cost, W1, b1, W2, b2, beta,
                                       Vsum, hbh, hbl);

    dim3 g3(8, 24, 1);
    oproj_kernel<<<g3, 256, 0, stream>>>(hbh, hbl, woh, wol, bo, out);
}